// Round 6
// baseline (132.651 us; speedup 1.0000x reference)
//
#include <hip/hip_runtime.h>

// out[b,p] = sum_{e,f} x[b,i_p,e] * K[f,p,e] * x[b,j_p,f]
//
// R6: two dispatches.
//  1) prep: x fp32 -> xh/xl bf16 (trunc-hi split)  ||  K -> B-fragment-packed hi/lo
//  2) main: per (pair, 128-row tile): Y = Xj @ K_p via split-3 bf16 MFMA
//           (Ah*Bh + Ah*Bl + Al*Bh), epilogue rowsum(Y .* Xi) in fp32.
//
// Wave tile 32x64 (acc = 32 VGPR) so the full fragment set stays in registers
// (R3/R4/R5 all starved at 64x64: compiler capped ~80-104 VGPR -> serialized
// loads or scratch spill, MfmaUtil ~14%). 4 waves/block = 128 rows/block.
// Pair-pinned XCD mapping: p = bid % 496 (496 % 8 == 0) -> K_p stays in one L2.

constexpr int BATCH  = 2048;
constexpr int FIELDS = 32;
constexpr int EMBED  = 64;
constexpr int PAIRS  = FIELDS * (FIELDS - 1) / 2;  // 496

typedef __attribute__((ext_vector_type(8))) short  short8;   // 8 bf16 = 4 VGPR
typedef __attribute__((ext_vector_type(4))) float  f32x4;

constexpr size_t XN      = (size_t)BATCH * FIELDS * EMBED;   // 4,194,304
constexpr size_t KPN     = (size_t)PAIRS * 2 * 4 * 64 * 8;   // 2,031,616
constexpr size_t XH_OFF  = 0;
constexpr size_t XL_OFF  = XH_OFF + XN * 2;
constexpr size_t KPH_OFF = XL_OFF + XN * 2;
constexpr size_t KPL_OFF = KPH_OFF + KPN * 2;
constexpr size_t WS_NEED = KPL_OFF + KPN * 2;                // ~24.9 MB

constexpr int XSPLIT_BLOCKS = (int)(XN / 4 / 256);           // 4096
constexpr int KPACK_BLOCKS  = (int)(PAIRS * 512 / 256);      // 992

__device__ __forceinline__ unsigned short bf16_rne(float f) {
    unsigned int u = __float_as_uint(f);
    u = u + 0x7fffu + ((u >> 16) & 1u);
    return (unsigned short)(u >> 16);
}

// ---- Prep: x-split (blocks [0, 4096)) and K-pack (blocks [4096, 5088)) ----
__global__ __launch_bounds__(256) void prep_kernel(
    const float* __restrict__ x,
    const float* __restrict__ kern,
    unsigned short* __restrict__ xh,
    unsigned short* __restrict__ xl,
    unsigned short* __restrict__ kph,
    unsigned short* __restrict__ kpl)
{
    const int bid = (int)blockIdx.x;
    const int tid = (int)threadIdx.x;

    if (bid < XSPLIT_BLOCKS) {
        // x -> hi (trunc) / lo (rne residual), 4 floats per thread
        const int idx = bid * 256 + tid;
        const float4 v = ((const float4*)x)[idx];
        const float vv[4] = {v.x, v.y, v.z, v.w};
        unsigned short h[4], l[4];
        #pragma unroll
        for (int j = 0; j < 4; ++j) {
            const unsigned int u = __float_as_uint(vv[j]);
            h[j] = (unsigned short)(u >> 16);
            l[j] = bf16_rne(vv[j] - __uint_as_float(u & 0xffff0000u));
        }
        ((ushort4*)xh)[idx] = make_ushort4(h[0], h[1], h[2], h[3]);
        ((ushort4*)xl)[idx] = make_ushort4(l[0], l[1], l[2], l[3]);
    } else {
        // K -> packed B-fragments: chunk t = ((pair*2 + ks)*4 + nc)*64 + lane,
        // elem jj: f = ks*32 + (lane>>4)*8 + jj, e = nc*16 + (lane&15)
        const int t    = (bid - XSPLIT_BLOCKS) * 256 + tid;  // < PAIRS*512
        const int lane = t & 63;
        const int nc   = (t >> 6) & 3;
        const int ks   = (t >> 8) & 1;
        const int pair = t >> 9;
        const int e    = nc * 16 + (lane & 15);
        const int f0   = ks * 32 + (lane >> 4) * 8;

        short8 h8, l8;
        #pragma unroll
        for (int jj = 0; jj < 8; ++jj) {
            const float v = kern[((size_t)(f0 + jj) * PAIRS + pair) * EMBED + e];
            const unsigned int u = __float_as_uint(v);
            h8[jj] = (short)(u >> 16);
            l8[jj] = (short)bf16_rne(v - __uint_as_float(u & 0xffff0000u));
        }
        *(short8*)(kph + (size_t)t * 8) = h8;
        *(short8*)(kpl + (size_t)t * 8) = l8;
    }
}

// ---- Main: grid = 496 pairs * 16 row-tiles; block = 4 waves; wave = 32x64 ----
__global__ __launch_bounds__(256, 3) void opn_mfma_kernel(
    const float* __restrict__ x,
    const unsigned short* __restrict__ xh,
    const unsigned short* __restrict__ xl,
    const unsigned short* __restrict__ kph,
    const unsigned short* __restrict__ kpl,
    float* __restrict__ out)
{
    const int bid  = (int)blockIdx.x;
    const int p    = bid % PAIRS;              // pair-pinned: XCD = p % 8
    const int mt   = bid / PAIRS;              // 0..15, 128-row tiles
    const int wave = (int)threadIdx.x >> 6;
    const int lane = (int)threadIdx.x & 63;
    const int Mb   = mt * 128 + wave * 32;     // this wave's first batch row
    const int g    = lane >> 4;
    const int c    = lane & 15;

    // pair -> (i, j) per jnp.triu_indices(FIELDS, k=1)
    int i = 0, rem = p;
    while (rem >= FIELDS - 1 - i) { rem -= FIELDS - 1 - i; ++i; }
    const int jf = i + 1 + rem;

    f32x4 acc[2][4];
    #pragma unroll
    for (int mr = 0; mr < 2; ++mr)
        #pragma unroll
        for (int nc = 0; nc < 4; ++nc)
            acc[mr][nc] = (f32x4){0.f, 0.f, 0.f, 0.f};

    #pragma unroll
    for (int ks = 0; ks < 2; ++ks) {
        // A fragments (validated mapping): row = Mb + mr*16 + c, k = ks*32 + g*8 ..+7
        short8 ah[2], al[2];
        #pragma unroll
        for (int mr = 0; mr < 2; ++mr) {
            const int row = Mb + mr * 16 + c;
            const size_t off = ((size_t)row * FIELDS + jf) * EMBED + ks * 32 + g * 8;
            ah[mr] = *(const short8*)(xh + off);
            al[mr] = *(const short8*)(xl + off);
        }
        // B fragments (validated packed layout), 16B/lane coalesced
        short8 bh[4], bl[4];
        #pragma unroll
        for (int nc = 0; nc < 4; ++nc) {
            const size_t kidx = (((size_t)(p * 2 + ks) * 4 + nc) * 64 + lane) * 8;
            bh[nc] = *(const short8*)(kph + kidx);
            bl[nc] = *(const short8*)(kpl + kidx);
        }
        #pragma unroll
        for (int mr = 0; mr < 2; ++mr)
            #pragma unroll
            for (int nc = 0; nc < 4; ++nc) {
                acc[mr][nc] = __builtin_amdgcn_mfma_f32_16x16x32_bf16(ah[mr], bh[nc], acc[mr][nc], 0, 0, 0);
                acc[mr][nc] = __builtin_amdgcn_mfma_f32_16x16x32_bf16(ah[mr], bl[nc], acc[mr][nc], 0, 0, 0);
                acc[mr][nc] = __builtin_amdgcn_mfma_f32_16x16x32_bf16(al[mr], bh[nc], acc[mr][nc], 0, 0, 0);
            }
    }

    // ---- Epilogue: out[row, p] = sum_e D[row][e] * x[row][i][e] ----
    // D layout (validated): reg t of acc[mr][nc] = D[Mb + mr*16 + 4g + t][nc*16 + c]
    float z[2][4];
    #pragma unroll
    for (int mr = 0; mr < 2; ++mr)
        #pragma unroll
        for (int t = 0; t < 4; ++t)
            z[mr][t] = 0.f;

    const size_t xi_base = (size_t)i * EMBED + c;
    #pragma unroll
    for (int mr = 0; mr < 2; ++mr)
        #pragma unroll
        for (int t = 0; t < 4; ++t) {
            const int row = Mb + mr * 16 + 4 * g + t;
            const float* xi = x + (size_t)row * (FIELDS * EMBED) + xi_base;
            #pragma unroll
            for (int nc = 0; nc < 4; ++nc)
                z[mr][t] = fmaf(acc[mr][nc][t], xi[nc * 16], z[mr][t]);
        }

    #pragma unroll
    for (int mask = 1; mask < 16; mask <<= 1)
        #pragma unroll
        for (int mr = 0; mr < 2; ++mr)
            #pragma unroll
            for (int t = 0; t < 4; ++t)
                z[mr][t] += __shfl_xor(z[mr][t], mask, 64);

    if (c < 4) {  // lane c==t writes rows {Mb + mr*16 + 4g + t}
        const int t = c;
        #pragma unroll
        for (int mr = 0; mr < 2; ++mr) {
            const int row = Mb + mr * 16 + 4 * g + t;
            out[(size_t)row * PAIRS + p] = z[mr][t];
        }
    }
}

// ---- fp32 VALU fallback (only if ws too small) ----
__global__ __launch_bounds__(64) void opn_fp32_kernel(
    const float* __restrict__ x,
    const float* __restrict__ kern,
    float* __restrict__ out)
{
    const int bid   = (int)blockIdx.x;
    const int p     = bid >> 5;
    const int btile = bid & 31;
    const int lane  = (int)threadIdx.x;
    const int b     = btile * 64 + lane;

    int i = 0, rem = p;
    while (rem >= FIELDS - 1 - i) { rem -= FIELDS - 1 - i; ++i; }
    const int j = i + 1 + rem;

    const float* xrow_i = x + (size_t)b * (FIELDS * EMBED) + i * EMBED;
    const float* xrow_j = x + (size_t)b * (FIELDS * EMBED) + j * EMBED;
    const float* kp     = kern + (size_t)p * EMBED;

    float acc[EMBED];
    #pragma unroll
    for (int e = 0; e < EMBED; ++e) acc[e] = 0.0f;

    const float4* xj4 = (const float4*)xrow_j;
    #pragma unroll 2
    for (int f4 = 0; f4 < EMBED / 4; ++f4) {
        const float4 v = xj4[f4];
        const float xjf[4] = {v.x, v.y, v.z, v.w};
        #pragma unroll
        for (int s = 0; s < 4; ++s) {
            const float* kf = kp + (size_t)(f4 * 4 + s) * (PAIRS * EMBED);
            #pragma unroll
            for (int e = 0; e < EMBED; ++e)
                acc[e] = fmaf(xjf[s], kf[e], acc[e]);
        }
    }

    float r = 0.0f;
    const float4* xi4 = (const float4*)xrow_i;
    #pragma unroll
    for (int e4 = 0; e4 < EMBED / 4; ++e4) {
        const float4 u = xi4[e4];
        r = fmaf(u.x, acc[e4 * 4 + 0], r);
        r = fmaf(u.y, acc[e4 * 4 + 1], r);
        r = fmaf(u.z, acc[e4 * 4 + 2], r);
        r = fmaf(u.w, acc[e4 * 4 + 3], r);
    }
    out[(size_t)b * PAIRS + p] = r;
}

extern "C" void kernel_launch(void* const* d_in, const int* in_sizes, int n_in,
                              void* d_out, int out_size, void* d_ws, size_t ws_size,
                              hipStream_t stream) {
    const float* x    = (const float*)d_in[0];
    const float* kern = (const float*)d_in[1];
    float*       out  = (float*)d_out;

    if (ws_size < WS_NEED) {
        opn_fp32_kernel<<<dim3(PAIRS * 32), dim3(64), 0, stream>>>(x, kern, out);
        return;
    }

    char* ws = (char*)d_ws;
    unsigned short* xhi = (unsigned short*)(ws + XH_OFF);
    unsigned short* xlo = (unsigned short*)(ws + XL_OFF);
    unsigned short* kph = (unsigned short*)(ws + KPH_OFF);
    unsigned short* kpl = (unsigned short*)(ws + KPL_OFF);

    prep_kernel<<<dim3(XSPLIT_BLOCKS + KPACK_BLOCKS), dim3(256), 0, stream>>>(
        x, kern, xhi, xlo, kph, kpl);
    opn_mfma_kernel<<<dim3(PAIRS * 16), dim3(256), 0, stream>>>(
        x, xhi, xlo, kph, kpl, out);
}

// Round 7
// 129.411 us; speedup vs baseline: 1.0250x; 1.0250x over previous
//
#include <hip/hip_runtime.h>

// out[b,p] = sum_{e,f} x[b,i_p,e] * K[f,p,e] * x[b,j_p,f]
//
// R7: per-pair GEMM with a LONG row-loop (pipelineable), B resident in regs.
//   Y[b,f] = sum_e x[b,i_p,e] * Kt_p[e,f]   (Kt_p[e,f] = K[f,p,e], split-3 bf16 MFMA)
//   out[b,p] = sum_f Y[b,f] * x[b,j_p,f]    (fp32 VALU epilogue)
//
// Two dispatches:
//  1) prep: x -> xh/xl (bf16 trunc-hi split)  ||  K -> B-fragment-packed Kt hi/lo
//  2) main: 496 blocks (one per pair), 4 waves; wave loops 16 row-tiles of 32.
//     B-frags (64 VGPR) live across the whole loop; A streamed per iteration.
//
// R3-R6 lesson: one-shot blocks (load->MFMA->exit) are latency-bound (~6us/block,
// MfmaUtil 14%). The 16-iteration loop gives hipcc a window to software-pipeline
// (m97 pattern). No XCD pinning (R6's pinning amplified FETCH 40->122MB, WRITE
// 4->32MB via cross-XCD partial-line writes).

constexpr int BATCH  = 2048;
constexpr int FIELDS = 32;
constexpr int EMBED  = 64;
constexpr int PAIRS  = FIELDS * (FIELDS - 1) / 2;  // 496

typedef __attribute__((ext_vector_type(8))) short  short8;   // 8 bf16 = 4 VGPR
typedef __attribute__((ext_vector_type(4))) float  f32x4;

constexpr size_t XN      = (size_t)BATCH * FIELDS * EMBED;   // 4,194,304
constexpr size_t KPN     = (size_t)PAIRS * 2 * 4 * 64 * 8;   // 2,031,616
constexpr size_t XH_OFF  = 0;
constexpr size_t XL_OFF  = XH_OFF + XN * 2;
constexpr size_t KPH_OFF = XL_OFF + XN * 2;
constexpr size_t KPL_OFF = KPH_OFF + KPN * 2;
constexpr size_t WS_NEED = KPL_OFF + KPN * 2;                // ~24.9 MB

constexpr int XSPLIT_BLOCKS = (int)(XN / 4 / 256);           // 4096
constexpr int KPACK_BLOCKS  = (int)(PAIRS * 512 / 256);      // 992

__device__ __forceinline__ unsigned short bf16_rne(float f) {
    unsigned int u = __float_as_uint(f);
    u = u + 0x7fffu + ((u >> 16) & 1u);
    return (unsigned short)(u >> 16);
}

// ---- Prep: x-split (blocks [0,4096)) and Kt-pack (blocks [4096,5088)) ----
__global__ __launch_bounds__(256) void prep_kernel(
    const float* __restrict__ x,
    const float* __restrict__ kern,
    unsigned short* __restrict__ xh,
    unsigned short* __restrict__ xl,
    unsigned short* __restrict__ kph,
    unsigned short* __restrict__ kpl)
{
    const int bid = (int)blockIdx.x;
    const int tid = (int)threadIdx.x;

    if (bid < XSPLIT_BLOCKS) {
        const int idx = bid * 256 + tid;
        const float4 v = ((const float4*)x)[idx];
        const float vv[4] = {v.x, v.y, v.z, v.w};
        unsigned short h[4], l[4];
        #pragma unroll
        for (int j = 0; j < 4; ++j) {
            const unsigned int u = __float_as_uint(vv[j]);
            h[j] = (unsigned short)(u >> 16);
            l[j] = bf16_rne(vv[j] - __uint_as_float(u & 0xffff0000u));
        }
        ((ushort4*)xh)[idx] = make_ushort4(h[0], h[1], h[2], h[3]);
        ((ushort4*)xl)[idx] = make_ushort4(l[0], l[1], l[2], l[3]);
    } else {
        // Kt pack: B[k=e][n=f] = K[f,p,e]. chunk t = ((pair*2+ks)*4+nc)*64+lane,
        // elem jj: e = ks*32 + (lane>>4)*8 + jj (contiguous in kern!), f = nc*16 + (lane&15)
        const int t    = (bid - XSPLIT_BLOCKS) * 256 + tid;  // < PAIRS*512
        const int lane = t & 63;
        const int nc   = (t >> 6) & 3;
        const int ks   = (t >> 8) & 1;
        const int pair = t >> 9;
        const int f    = nc * 16 + (lane & 15);
        const int e0   = ks * 32 + (lane >> 4) * 8;

        const float* src = kern + ((size_t)f * PAIRS + pair) * EMBED + e0;
        const float4 v0 = *(const float4*)(src);
        const float4 v1 = *(const float4*)(src + 4);
        const float vv[8] = {v0.x, v0.y, v0.z, v0.w, v1.x, v1.y, v1.z, v1.w};

        short8 h8, l8;
        #pragma unroll
        for (int jj = 0; jj < 8; ++jj) {
            const unsigned int u = __float_as_uint(vv[jj]);
            h8[jj] = (short)(u >> 16);
            l8[jj] = (short)bf16_rne(vv[jj] - __uint_as_float(u & 0xffff0000u));
        }
        *(short8*)(kph + (size_t)t * 8) = h8;
        *(short8*)(kpl + (size_t)t * 8) = l8;
    }
}

// ---- Main: 496 blocks (one per pair); wave loops 16 row-tiles of 32 rows ----
__global__ __launch_bounds__(256, 2) void opn_mfma_kernel(
    const float* __restrict__ x,
    const unsigned short* __restrict__ xh,
    const unsigned short* __restrict__ xl,
    const unsigned short* __restrict__ kph,
    const unsigned short* __restrict__ kpl,
    float* __restrict__ out)
{
    const int p    = (int)blockIdx.x;
    const int wave = (int)threadIdx.x >> 6;
    const int lane = (int)threadIdx.x & 63;
    const int g    = lane >> 4;
    const int c    = lane & 15;

    // pair -> (i, j) per jnp.triu_indices(FIELDS, k=1)
    int i = 0, rem = p;
    while (rem >= FIELDS - 1 - i) { rem -= FIELDS - 1 - i; ++i; }
    const int jf = i + 1 + rem;
    // A-side field = i (first index), epilogue field = jf (second index)

    // ---- B fragments: load once, resident for the whole kernel (64 VGPR) ----
    short8 bh[2][4], bl[2][4];
    #pragma unroll
    for (int ks = 0; ks < 2; ++ks)
        #pragma unroll
        for (int nc = 0; nc < 4; ++nc) {
            const size_t kidx = (((size_t)(p * 2 + ks) * 4 + nc) * 64 + lane) * 8;
            bh[ks][nc] = *(const short8*)(kph + kidx);
            bl[ks][nc] = *(const short8*)(kpl + kidx);
        }

    // ---- Row loop: 16 iterations x 32 rows ----
    for (int it = 0; it < 16; ++it) {
        const int Mb = it * 128 + wave * 32;

        // A fragments (validated mapping): row = Mb + mr*16 + c, k(e) = ks*32 + g*8..+7
        short8 ah[2][2], al[2][2];  // [mr][ks]
        #pragma unroll
        for (int mr = 0; mr < 2; ++mr) {
            const int row = Mb + mr * 16 + c;
            const size_t off0 = ((size_t)row * FIELDS + i) * EMBED + g * 8;
            #pragma unroll
            for (int ks = 0; ks < 2; ++ks) {
                ah[mr][ks] = *(const short8*)(xh + off0 + ks * 32);
                al[mr][ks] = *(const short8*)(xl + off0 + ks * 32);
            }
        }

        f32x4 acc[2][4];
        #pragma unroll
        for (int mr = 0; mr < 2; ++mr)
            #pragma unroll
            for (int nc = 0; nc < 4; ++nc)
                acc[mr][nc] = (f32x4){0.f, 0.f, 0.f, 0.f};

        #pragma unroll
        for (int ks = 0; ks < 2; ++ks)
            #pragma unroll
            for (int mr = 0; mr < 2; ++mr)
                #pragma unroll
                for (int nc = 0; nc < 4; ++nc) {
                    acc[mr][nc] = __builtin_amdgcn_mfma_f32_16x16x32_bf16(ah[mr][ks], bh[ks][nc], acc[mr][nc], 0, 0, 0);
                    acc[mr][nc] = __builtin_amdgcn_mfma_f32_16x16x32_bf16(ah[mr][ks], bl[ks][nc], acc[mr][nc], 0, 0, 0);
                    acc[mr][nc] = __builtin_amdgcn_mfma_f32_16x16x32_bf16(al[mr][ks], bh[ks][nc], acc[mr][nc], 0, 0, 0);
                }

        // Epilogue: out[row,p] = sum_f D[row][f] * x[row][jf][f]
        // D layout (validated): reg t of acc[mr][nc] = D[Mb+mr*16+4g+t][f = nc*16+c]
        float z[2][4];
        #pragma unroll
        for (int mr = 0; mr < 2; ++mr)
            #pragma unroll
            for (int t = 0; t < 4; ++t)
                z[mr][t] = 0.f;

        const size_t xj_base = (size_t)jf * EMBED + c;
        #pragma unroll
        for (int mr = 0; mr < 2; ++mr)
            #pragma unroll
            for (int t = 0; t < 4; ++t) {
                const int row = Mb + mr * 16 + 4 * g + t;
                const float* xj = x + (size_t)row * (FIELDS * EMBED) + xj_base;
                #pragma unroll
                for (int nc = 0; nc < 4; ++nc)
                    z[mr][t] = fmaf(acc[mr][nc][t], xj[nc * 16], z[mr][t]);
            }

        #pragma unroll
        for (int mask = 1; mask < 16; mask <<= 1)
            #pragma unroll
            for (int mr = 0; mr < 2; ++mr)
                #pragma unroll
                for (int t = 0; t < 4; ++t)
                    z[mr][t] += __shfl_xor(z[mr][t], mask, 64);

        if (c < 4) {  // lane c==t writes rows {Mb + mr*16 + 4g + t}
            const int t = c;
            #pragma unroll
            for (int mr = 0; mr < 2; ++mr) {
                const int row = Mb + mr * 16 + 4 * g + t;
                out[(size_t)row * PAIRS + p] = z[mr][t];
            }
        }
    }
}

// ---- fp32 VALU fallback (only if ws too small) ----
__global__ __launch_bounds__(64) void opn_fp32_kernel(
    const float* __restrict__ x,
    const float* __restrict__ kern,
    float* __restrict__ out)
{
    const int bid   = (int)blockIdx.x;
    const int p     = bid >> 5;
    const int btile = bid & 31;
    const int lane  = (int)threadIdx.x;
    const int b     = btile * 64 + lane;

    int i = 0, rem = p;
    while (rem >= FIELDS - 1 - i) { rem -= FIELDS - 1 - i; ++i; }
    const int j = i + 1 + rem;

    const float* xrow_i = x + (size_t)b * (FIELDS * EMBED) + i * EMBED;
    const float* xrow_j = x + (size_t)b * (FIELDS * EMBED) + j * EMBED;
    const float* kp     = kern + (size_t)p * EMBED;

    float acc[EMBED];
    #pragma unroll
    for (int e = 0; e < EMBED; ++e) acc[e] = 0.0f;

    const float4* xj4 = (const float4*)xrow_j;
    #pragma unroll 2
    for (int f4 = 0; f4 < EMBED / 4; ++f4) {
        const float4 v = xj4[f4];
        const float xjf[4] = {v.x, v.y, v.z, v.w};
        #pragma unroll
        for (int s = 0; s < 4; ++s) {
            const float* kf = kp + (size_t)(f4 * 4 + s) * (PAIRS * EMBED);
            #pragma unroll
            for (int e = 0; e < EMBED; ++e)
                acc[e] = fmaf(xjf[s], kf[e], acc[e]);
        }
    }

    float r = 0.0f;
    const float4* xi4 = (const float4*)xrow_i;
    #pragma unroll
    for (int e4 = 0; e4 < EMBED / 4; ++e4) {
        const float4 u = xi4[e4];
        r = fmaf(u.x, acc[e4 * 4 + 0], r);
        r = fmaf(u.y, acc[e4 * 4 + 1], r);
        r = fmaf(u.z, acc[e4 * 4 + 2], r);
        r = fmaf(u.w, acc[e4 * 4 + 3], r);
    }
    out[(size_t)b * PAIRS + p] = r;
}

extern "C" void kernel_launch(void* const* d_in, const int* in_sizes, int n_in,
                              void* d_out, int out_size, void* d_ws, size_t ws_size,
                              hipStream_t stream) {
    const float* x    = (const float*)d_in[0];
    const float* kern = (const float*)d_in[1];
    float*       out  = (float*)d_out;

    if (ws_size < WS_NEED) {
        opn_fp32_kernel<<<dim3(PAIRS * 32), dim3(64), 0, stream>>>(x, kern, out);
        return;
    }

    char* ws = (char*)d_ws;
    unsigned short* xhi = (unsigned short*)(ws + XH_OFF);
    unsigned short* xlo = (unsigned short*)(ws + XL_OFF);
    unsigned short* kph = (unsigned short*)(ws + KPH_OFF);
    unsigned short* kpl = (unsigned short*)(ws + KPL_OFF);

    prep_kernel<<<dim3(XSPLIT_BLOCKS + KPACK_BLOCKS), dim3(256), 0, stream>>>(
        x, kern, xhi, xlo, kph, kpl);
    opn_mfma_kernel<<<dim3(PAIRS), dim3(256), 0, stream>>>(
        x, xhi, xlo, kph, kpl, out);
}

// Round 11
// 127.407 us; speedup vs baseline: 1.0412x; 1.0157x over previous
//
#include <hip/hip_runtime.h>

// out[b,p] = sum_{e,f} x[b,i_p,e] * K[f,p,e] * x[b,j_p,f]
//
// R8 (3rd resubmit; GPU timeouts): R6's validated 32x64-wave-tile kernel
// + R4's p-major block ordering.
//
//   bid = p*16 + mt  (p-major). All 16 blocks writing a given 64B out-line
//   (16 consecutive p of one row) share bid%8 -> same XCD -> full-line
//   coalescing in one L2. R5/R6/R7 violated this and paid WRITE 32MB vs 4MB
//   + RMW fetch amplification. R4 (p-major) measured WRITE 4.1MB, FETCH 40MB.
//
// Two dispatches:
//  1) prep: x -> xh/xl (bf16 trunc-hi split)  ||  K -> B-fragment-packed hi/lo
//  2) main: grid 496*16, 4 waves/block, wave = 32 rows x 64 e, split-3 MFMA
//           (Ah*Bh + Ah*Bl + Al*Bh), fp32 epilogue rowsum(Y .* Xi).

constexpr int BATCH  = 2048;
constexpr int FIELDS = 32;
constexpr int EMBED  = 64;
constexpr int PAIRS  = FIELDS * (FIELDS - 1) / 2;  // 496

typedef __attribute__((ext_vector_type(8))) short  short8;   // 8 bf16 = 4 VGPR
typedef __attribute__((ext_vector_type(4))) float  f32x4;

constexpr size_t XN      = (size_t)BATCH * FIELDS * EMBED;   // 4,194,304
constexpr size_t KPN     = (size_t)PAIRS * 2 * 4 * 64 * 8;   // 2,031,616
constexpr size_t XH_OFF  = 0;
constexpr size_t XL_OFF  = XH_OFF + XN * 2;
constexpr size_t KPH_OFF = XL_OFF + XN * 2;
constexpr size_t KPL_OFF = KPH_OFF + KPN * 2;
constexpr size_t WS_NEED = KPL_OFF + KPN * 2;                // ~24.9 MB

constexpr int XSPLIT_BLOCKS = (int)(XN / 4 / 256);           // 4096
constexpr int KPACK_BLOCKS  = (int)(PAIRS * 512 / 256);      // 992

__device__ __forceinline__ unsigned short bf16_rne(float f) {
    unsigned int u = __float_as_uint(f);
    u = u + 0x7fffu + ((u >> 16) & 1u);
    return (unsigned short)(u >> 16);
}

// ---- Prep: x-split (blocks [0,4096)) and K-pack (blocks [4096,5088)) ----
__global__ __launch_bounds__(256) void prep_kernel(
    const float* __restrict__ x,
    const float* __restrict__ kern,
    unsigned short* __restrict__ xh,
    unsigned short* __restrict__ xl,
    unsigned short* __restrict__ kph,
    unsigned short* __restrict__ kpl)
{
    const int bid = (int)blockIdx.x;
    const int tid = (int)threadIdx.x;

    if (bid < XSPLIT_BLOCKS) {
        const int idx = bid * 256 + tid;
        const float4 v = ((const float4*)x)[idx];
        const float vv[4] = {v.x, v.y, v.z, v.w};
        unsigned short h[4], l[4];
        #pragma unroll
        for (int j = 0; j < 4; ++j) {
            const unsigned int u = __float_as_uint(vv[j]);
            h[j] = (unsigned short)(u >> 16);
            l[j] = bf16_rne(vv[j] - __uint_as_float(u & 0xffff0000u));
        }
        ((ushort4*)xh)[idx] = make_ushort4(h[0], h[1], h[2], h[3]);
        ((ushort4*)xl)[idx] = make_ushort4(l[0], l[1], l[2], l[3]);
    } else {
        // K -> packed B-fragments: chunk t = ((pair*2 + ks)*4 + nc)*64 + lane,
        // elem jj: f = ks*32 + (lane>>4)*8 + jj, e = nc*16 + (lane&15)
        const int t    = (bid - XSPLIT_BLOCKS) * 256 + tid;  // < PAIRS*512
        const int lane = t & 63;
        const int nc   = (t >> 6) & 3;
        const int ks   = (t >> 8) & 1;
        const int pair = t >> 9;
        const int e    = nc * 16 + (lane & 15);
        const int f0   = ks * 32 + (lane >> 4) * 8;

        short8 h8, l8;
        #pragma unroll
        for (int jj = 0; jj < 8; ++jj) {
            const float v = kern[((size_t)(f0 + jj) * PAIRS + pair) * EMBED + e];
            const unsigned int u = __float_as_uint(v);
            h8[jj] = (short)(u >> 16);
            l8[jj] = (short)bf16_rne(v - __uint_as_float(u & 0xffff0000u));
        }
        *(short8*)(kph + (size_t)t * 8) = h8;
        *(short8*)(kpl + (size_t)t * 8) = l8;
    }
}

// ---- Main: grid = 496*16 p-major; block = 4 waves; wave = 32 rows x 64 e ----
__global__ __launch_bounds__(256, 3) void opn_mfma_kernel(
    const float* __restrict__ x,
    const unsigned short* __restrict__ xh,
    const unsigned short* __restrict__ xl,
    const unsigned short* __restrict__ kph,
    const unsigned short* __restrict__ kpl,
    float* __restrict__ out)
{
    const int bid  = (int)blockIdx.x;
    const int p    = bid >> 4;                 // p-major: 16 consecutive bids share p
    const int mt   = bid & 15;                 // 128-row tile
    const int wave = (int)threadIdx.x >> 6;
    const int lane = (int)threadIdx.x & 63;
    const int Mb   = mt * 128 + wave * 32;     // this wave's first batch row
    const int g    = lane >> 4;
    const int c    = lane & 15;

    // pair -> (i, j) per jnp.triu_indices(FIELDS, k=1)
    int i = 0, rem = p;
    while (rem >= FIELDS - 1 - i) { rem -= FIELDS - 1 - i; ++i; }
    const int jf = i + 1 + rem;

    f32x4 acc[2][4];
    #pragma unroll
    for (int mr = 0; mr < 2; ++mr)
        #pragma unroll
        for (int nc = 0; nc < 4; ++nc)
            acc[mr][nc] = (f32x4){0.f, 0.f, 0.f, 0.f};

    #pragma unroll
    for (int ks = 0; ks < 2; ++ks) {
        // A fragments (validated): row = Mb + mr*16 + c, k(f) = ks*32 + g*8..+7
        short8 ah[2], al[2];
        #pragma unroll
        for (int mr = 0; mr < 2; ++mr) {
            const int row = Mb + mr * 16 + c;
            const size_t off = ((size_t)row * FIELDS + jf) * EMBED + ks * 32 + g * 8;
            ah[mr] = *(const short8*)(xh + off);
            al[mr] = *(const short8*)(xl + off);
        }
        // B fragments (validated packed layout), 16B/lane coalesced
        short8 bh[4], bl[4];
        #pragma unroll
        for (int nc = 0; nc < 4; ++nc) {
            const size_t kidx = (((size_t)(p * 2 + ks) * 4 + nc) * 64 + lane) * 8;
            bh[nc] = *(const short8*)(kph + kidx);
            bl[nc] = *(const short8*)(kpl + kidx);
        }
        #pragma unroll
        for (int mr = 0; mr < 2; ++mr)
            #pragma unroll
            for (int nc = 0; nc < 4; ++nc) {
                acc[mr][nc] = __builtin_amdgcn_mfma_f32_16x16x32_bf16(ah[mr], bh[nc], acc[mr][nc], 0, 0, 0);
                acc[mr][nc] = __builtin_amdgcn_mfma_f32_16x16x32_bf16(ah[mr], bl[nc], acc[mr][nc], 0, 0, 0);
                acc[mr][nc] = __builtin_amdgcn_mfma_f32_16x16x32_bf16(al[mr], bh[nc], acc[mr][nc], 0, 0, 0);
            }
    }

    // ---- Epilogue: out[row, p] = sum_e D[row][e] * x[row][i][e] ----
    // D layout (validated): reg t of acc[mr][nc] = D[Mb + mr*16 + 4g + t][nc*16 + c]
    float z[2][4];
    #pragma unroll
    for (int mr = 0; mr < 2; ++mr)
        #pragma unroll
        for (int t = 0; t < 4; ++t)
            z[mr][t] = 0.f;

    const size_t xi_base = (size_t)i * EMBED + c;
    #pragma unroll
    for (int mr = 0; mr < 2; ++mr)
        #pragma unroll
        for (int t = 0; t < 4; ++t) {
            const int row = Mb + mr * 16 + 4 * g + t;
            const float* xi = x + (size_t)row * (FIELDS * EMBED) + xi_base;
            #pragma unroll
            for (int nc = 0; nc < 4; ++nc)
                z[mr][t] = fmaf(acc[mr][nc][t], xi[nc * 16], z[mr][t]);
        }

    #pragma unroll
    for (int mask = 1; mask < 16; mask <<= 1)
        #pragma unroll
        for (int mr = 0; mr < 2; ++mr)
            #pragma unroll
            for (int t = 0; t < 4; ++t)
                z[mr][t] += __shfl_xor(z[mr][t], mask, 64);

    if (c < 4) {  // lane c==t writes rows {Mb + mr*16 + 4g + t}
        const int t = c;
        #pragma unroll
        for (int mr = 0; mr < 2; ++mr) {
            const int row = Mb + mr * 16 + 4 * g + t;
            out[(size_t)row * PAIRS + p] = z[mr][t];
        }
    }
}

// ---- fp32 VALU fallback (only if ws too small) ----
__global__ __launch_bounds__(64) void opn_fp32_kernel(
    const float* __restrict__ x,
    const float* __restrict__ kern,
    float* __restrict__ out)
{
    const int bid   = (int)blockIdx.x;
    const int p     = bid >> 5;
    const int btile = bid & 31;
    const int lane  = (int)threadIdx.x;
    const int b     = btile * 64 + lane;

    int i = 0, rem = p;
    while (rem >= FIELDS - 1 - i) { rem -= FIELDS - 1 - i; ++i; }
    const int j = i + 1 + rem;

    const float* xrow_i = x + (size_t)b * (FIELDS * EMBED) + i * EMBED;
    const float* xrow_j = x + (size_t)b * (FIELDS * EMBED) + j * EMBED;
    const float* kp     = kern + (size_t)p * EMBED;

    float acc[EMBED];
    #pragma unroll
    for (int e = 0; e < EMBED; ++e) acc[e] = 0.0f;

    const float4* xj4 = (const float4*)xrow_j;
    #pragma unroll 2
    for (int f4 = 0; f4 < EMBED / 4; ++f4) {
        const float4 v = xj4[f4];
        const float xjf[4] = {v.x, v.y, v.z, v.w};
        #pragma unroll
        for (int s = 0; s < 4; ++s) {
            const float* kf = kp + (size_t)(f4 * 4 + s) * (PAIRS * EMBED);
            #pragma unroll
            for (int e = 0; e < EMBED; ++e)
                acc[e] = fmaf(xjf[s], kf[e], acc[e]);
        }
    }

    float r = 0.0f;
    const float4* xi4 = (const float4*)xrow_i;
    #pragma unroll
    for (int e4 = 0; e4 < EMBED / 4; ++e4) {
        const float4 u = xi4[e4];
        r = fmaf(u.x, acc[e4 * 4 + 0], r);
        r = fmaf(u.y, acc[e4 * 4 + 1], r);
        r = fmaf(u.z, acc[e4 * 4 + 2], r);
        r = fmaf(u.w, acc[e4 * 4 + 3], r);
    }
    out[(size_t)b * PAIRS + p] = r;
}

extern "C" void kernel_launch(void* const* d_in, const int* in_sizes, int n_in,
                              void* d_out, int out_size, void* d_ws, size_t ws_size,
                              hipStream_t stream) {
    const float* x    = (const float*)d_in[0];
    const float* kern = (const float*)d_in[1];
    float*       out  = (float*)d_out;

    if (ws_size < WS_NEED) {
        opn_fp32_kernel<<<dim3(PAIRS * 32), dim3(64), 0, stream>>>(x, kern, out);
        return;
    }

    char* ws = (char*)d_ws;
    unsigned short* xhi = (unsigned short*)(ws + XH_OFF);
    unsigned short* xlo = (unsigned short*)(ws + XL_OFF);
    unsigned short* kph = (unsigned short*)(ws + KPH_OFF);
    unsigned short* kpl = (unsigned short*)(ws + KPL_OFF);

    prep_kernel<<<dim3(XSPLIT_BLOCKS + KPACK_BLOCKS), dim3(256), 0, stream>>>(
        x, kern, xhi, xlo, kph, kpl);
    opn_mfma_kernel<<<dim3(PAIRS * 16), dim3(256), 0, stream>>>(
        x, xhi, xlo, kph, kpl, out);
}

// Round 12
// 113.978 us; speedup vs baseline: 1.1638x; 1.1178x over previous
//
#include <hip/hip_runtime.h>

// out[b,p] = sum_{e,f} x[b,i_p,e] * K[f,p,e] * x[b,j_p,f]
//
// R9: R8 (validated numerics, p-major ordering, clean traffic) with the load
// path rebuilt on __builtin_amdgcn_global_load_lds.
//
// R8 diagnosis: per-wave span ~14.4k cy = ~58 VMEM x ~250cy FULLY SERIALIZED
// (VGPR=52: compiler holds one payload at a time). gload_lds needs no payload
// VGPRs -> 12 stage instrs in flight, ONE vmcnt drain, then LDS-latency reads.
//
// LDS (48KB): B-frags hi/lo 16KB (pair-contiguous in ws, staged linearly) +
// A (x_hi/x_lo rows) 32KB, XOR-swizzled (rule #21: linear LDS dest, inverse-
// swizzled GLOBAL source, swizzled ds_read) to kill the 128B-stride bank
// conflict. Epilogue identical to R8 (direct fp32 x reads, shfl reduce).

constexpr int BATCH  = 2048;
constexpr int FIELDS = 32;
constexpr int EMBED  = 64;
constexpr int PAIRS  = FIELDS * (FIELDS - 1) / 2;  // 496

typedef __attribute__((ext_vector_type(8))) short  short8;   // 8 bf16 = 4 VGPR
typedef __attribute__((ext_vector_type(4))) float  f32x4;

constexpr size_t XN      = (size_t)BATCH * FIELDS * EMBED;   // 4,194,304
constexpr size_t KPN     = (size_t)PAIRS * 2 * 4 * 64 * 8;   // 2,031,616
constexpr size_t XH_OFF  = 0;
constexpr size_t XL_OFF  = XH_OFF + XN * 2;
constexpr size_t KPH_OFF = XL_OFF + XN * 2;
constexpr size_t KPL_OFF = KPH_OFF + KPN * 2;
constexpr size_t WS_NEED = KPL_OFF + KPN * 2;                // ~24.9 MB

constexpr int XSPLIT_BLOCKS = (int)(XN / 4 / 256);           // 4096
constexpr int KPACK_BLOCKS  = (int)(PAIRS * 512 / 256);      // 992

__device__ __forceinline__ unsigned short bf16_rne(float f) {
    unsigned int u = __float_as_uint(f);
    u = u + 0x7fffu + ((u >> 16) & 1u);
    return (unsigned short)(u >> 16);
}

// ---- Prep: x-split (blocks [0,4096)) and K-pack (blocks [4096,5088)) ----
__global__ __launch_bounds__(256) void prep_kernel(
    const float* __restrict__ x,
    const float* __restrict__ kern,
    unsigned short* __restrict__ xh,
    unsigned short* __restrict__ xl,
    unsigned short* __restrict__ kph,
    unsigned short* __restrict__ kpl)
{
    const int bid = (int)blockIdx.x;
    const int tid = (int)threadIdx.x;

    if (bid < XSPLIT_BLOCKS) {
        const int idx = bid * 256 + tid;
        const float4 v = ((const float4*)x)[idx];
        const float vv[4] = {v.x, v.y, v.z, v.w};
        unsigned short h[4], l[4];
        #pragma unroll
        for (int j = 0; j < 4; ++j) {
            const unsigned int u = __float_as_uint(vv[j]);
            h[j] = (unsigned short)(u >> 16);
            l[j] = bf16_rne(vv[j] - __uint_as_float(u & 0xffff0000u));
        }
        ((ushort4*)xh)[idx] = make_ushort4(h[0], h[1], h[2], h[3]);
        ((ushort4*)xl)[idx] = make_ushort4(l[0], l[1], l[2], l[3]);
    } else {
        // K -> packed B-fragments: chunk t = ((pair*2 + ks)*4 + nc)*64 + lane,
        // elem jj: f = ks*32 + (lane>>4)*8 + jj, e = nc*16 + (lane&15)
        const int t    = (bid - XSPLIT_BLOCKS) * 256 + tid;  // < PAIRS*512
        const int lane = t & 63;
        const int nc   = (t >> 6) & 3;
        const int ks   = (t >> 8) & 1;
        const int pair = t >> 9;
        const int e    = nc * 16 + (lane & 15);
        const int f0   = ks * 32 + (lane >> 4) * 8;

        short8 h8, l8;
        #pragma unroll
        for (int jj = 0; jj < 8; ++jj) {
            const float v = kern[((size_t)(f0 + jj) * PAIRS + pair) * EMBED + e];
            const unsigned int u = __float_as_uint(v);
            h8[jj] = (short)(u >> 16);
            l8[jj] = (short)bf16_rne(v - __uint_as_float(u & 0xffff0000u));
        }
        *(short8*)(kph + (size_t)t * 8) = h8;
        *(short8*)(kpl + (size_t)t * 8) = l8;
    }
}

// ---- Main: grid = 496*16 p-major; 4 waves; wave = 32 rows x 64 e; LDS-staged ----
// LDS map (ushorts): [0,4096) B_hi | [4096,8192) B_lo | [8192,16384) A_hi | [16384,24576) A_lo
__global__ __launch_bounds__(256, 3) void opn_mfma_kernel(
    const float* __restrict__ x,
    const unsigned short* __restrict__ xh,
    const unsigned short* __restrict__ xl,
    const unsigned short* __restrict__ kph,
    const unsigned short* __restrict__ kpl,
    float* __restrict__ out)
{
    __shared__ unsigned short smem[24576];  // 48 KB

    const int bid  = (int)blockIdx.x;
    const int p    = bid >> 4;                 // p-major: 16 consecutive bids share p
    const int mt   = bid & 15;                 // 128-row tile
    const int tid  = (int)threadIdx.x;
    const int wave = tid >> 6;
    const int lane = tid & 63;
    const int Mb0  = mt * 128;
    const int Mb   = Mb0 + wave * 32;          // this wave's first batch row
    const int g    = lane >> 4;
    const int c    = lane & 15;

    // pair -> (i, j) per jnp.triu_indices(FIELDS, k=1)
    int i = 0, rem = p;
    while (rem >= FIELDS - 1 - i) { rem -= FIELDS - 1 - i; ++i; }
    const int jf = i + 1 + rem;

    // ---- Stage B (linear; layout already fragment-ordered, pair-contiguous) ----
    // chunks of 16B: q = tid + 256*k, k=0..1 (512 chunks = 8KB per buffer)
    #pragma unroll
    for (int k = 0; k < 2; ++k) {
        const int q = tid + 256 * k;
        unsigned short* ldst_h = &smem[(size_t)(k * 256 + wave * 64) * 8];
        unsigned short* ldst_l = &smem[4096 + (size_t)(k * 256 + wave * 64) * 8];
        __builtin_amdgcn_global_load_lds(kph + (size_t)p * 4096 + q * 8, ldst_h, 16, 0, 0);
        __builtin_amdgcn_global_load_lds(kpl + (size_t)p * 4096 + q * 8, ldst_l, 16, 0, 0);
    }

    // ---- Stage A rows [Mb0, Mb0+128), field jf, XOR-swizzled source ----
    // logical chunk (row, col16): LDS slot q = row*8 + col16 holds global col16^(row&7)
    #pragma unroll
    for (int k = 0; k < 4; ++k) {
        const int q   = tid + 256 * k;          // [0,1024)
        const int row = q >> 3;
        const int cs  = (q & 7) ^ (row & 7);    // inverse-swizzled source col16
        const size_t goff = ((size_t)(Mb0 + row) * FIELDS + jf) * EMBED + cs * 8;
        unsigned short* ldst_h = &smem[8192  + (size_t)(k * 256 + wave * 64) * 8];
        unsigned short* ldst_l = &smem[16384 + (size_t)(k * 256 + wave * 64) * 8];
        __builtin_amdgcn_global_load_lds(xh + goff, ldst_h, 16, 0, 0);
        __builtin_amdgcn_global_load_lds(xl + goff, ldst_l, 16, 0, 0);
    }

    asm volatile("s_waitcnt vmcnt(0)" ::: "memory");
    __syncthreads();

    // ---- MFMA (fragment reads from LDS; accumulation order identical to R8) ----
    f32x4 acc[2][4];
    #pragma unroll
    for (int mr = 0; mr < 2; ++mr)
        #pragma unroll
        for (int nc = 0; nc < 4; ++nc)
            acc[mr][nc] = (f32x4){0.f, 0.f, 0.f, 0.f};

    #pragma unroll
    for (int ks = 0; ks < 2; ++ks) {
        short8 ah[2], al[2];
        #pragma unroll
        for (int mr = 0; mr < 2; ++mr) {
            const int rl = wave * 32 + mr * 16 + c;           // row within block tile
            const int ch = rl * 8 + ((ks * 4 + g) ^ (rl & 7)); // swizzled chunk
            ah[mr] = *(const short8*)&smem[8192  + (size_t)ch * 8];
            al[mr] = *(const short8*)&smem[16384 + (size_t)ch * 8];
        }
        short8 bh[4], bl[4];
        #pragma unroll
        for (int nc = 0; nc < 4; ++nc) {
            const int off = ((ks * 4 + nc) * 64 + lane) * 8;
            bh[nc] = *(const short8*)&smem[off];
            bl[nc] = *(const short8*)&smem[4096 + off];
        }
        #pragma unroll
        for (int mr = 0; mr < 2; ++mr)
            #pragma unroll
            for (int nc = 0; nc < 4; ++nc) {
                acc[mr][nc] = __builtin_amdgcn_mfma_f32_16x16x32_bf16(ah[mr], bh[nc], acc[mr][nc], 0, 0, 0);
                acc[mr][nc] = __builtin_amdgcn_mfma_f32_16x16x32_bf16(ah[mr], bl[nc], acc[mr][nc], 0, 0, 0);
                acc[mr][nc] = __builtin_amdgcn_mfma_f32_16x16x32_bf16(al[mr], bh[nc], acc[mr][nc], 0, 0, 0);
            }
    }

    // ---- Epilogue (identical to R8): out[row,p] = sum_e D[row][e]*x[row][i][e] ----
    float z[2][4];
    #pragma unroll
    for (int mr = 0; mr < 2; ++mr)
        #pragma unroll
        for (int t = 0; t < 4; ++t)
            z[mr][t] = 0.f;

    const size_t xi_base = (size_t)i * EMBED + c;
    #pragma unroll
    for (int mr = 0; mr < 2; ++mr)
        #pragma unroll
        for (int t = 0; t < 4; ++t) {
            const int row = Mb + mr * 16 + 4 * g + t;
            const float* xi = x + (size_t)row * (FIELDS * EMBED) + xi_base;
            #pragma unroll
            for (int nc = 0; nc < 4; ++nc)
                z[mr][t] = fmaf(acc[mr][nc][t], xi[nc * 16], z[mr][t]);
        }

    #pragma unroll
    for (int mask = 1; mask < 16; mask <<= 1)
        #pragma unroll
        for (int mr = 0; mr < 2; ++mr)
            #pragma unroll
            for (int t = 0; t < 4; ++t)
                z[mr][t] += __shfl_xor(z[mr][t], mask, 64);

    if (c < 4) {  // lane c==t writes rows {Mb + mr*16 + 4g + t}
        const int t = c;
        #pragma unroll
        for (int mr = 0; mr < 2; ++mr) {
            const int row = Mb + mr * 16 + 4 * g + t;
            out[(size_t)row * PAIRS + p] = z[mr][t];
        }
    }
}

// ---- fp32 VALU fallback (only if ws too small) ----
__global__ __launch_bounds__(64) void opn_fp32_kernel(
    const float* __restrict__ x,
    const float* __restrict__ kern,
    float* __restrict__ out)
{
    const int bid   = (int)blockIdx.x;
    const int p     = bid >> 5;
    const int btile = bid & 31;
    const int lane  = (int)threadIdx.x;
    const int b     = btile * 64 + lane;

    int i = 0, rem = p;
    while (rem >= FIELDS - 1 - i) { rem -= FIELDS - 1 - i; ++i; }
    const int j = i + 1 + rem;

    const float* xrow_i = x + (size_t)b * (FIELDS * EMBED) + i * EMBED;
    const float* xrow_j = x + (size_t)b * (FIELDS * EMBED) + j * EMBED;
    const float* kp     = kern + (size_t)p * EMBED;

    float acc[EMBED];
    #pragma unroll
    for (int e = 0; e < EMBED; ++e) acc[e] = 0.0f;

    const float4* xj4 = (const float4*)xrow_j;
    #pragma unroll 2
    for (int f4 = 0; f4 < EMBED / 4; ++f4) {
        const float4 v = xj4[f4];
        const float xjf[4] = {v.x, v.y, v.z, v.w};
        #pragma unroll
        for (int s = 0; s < 4; ++s) {
            const float* kf = kp + (size_t)(f4 * 4 + s) * (PAIRS * EMBED);
            #pragma unroll
            for (int e = 0; e < EMBED; ++e)
                acc[e] = fmaf(xjf[s], kf[e], acc[e]);
        }
    }

    float r = 0.0f;
    const float4* xi4 = (const float4*)xrow_i;
    #pragma unroll
    for (int e4 = 0; e4 < EMBED / 4; ++e4) {
        const float4 u = xi4[e4];
        r = fmaf(u.x, acc[e4 * 4 + 0], r);
        r = fmaf(u.y, acc[e4 * 4 + 1], r);
        r = fmaf(u.z, acc[e4 * 4 + 2], r);
        r = fmaf(u.w, acc[e4 * 4 + 3], r);
    }
    out[(size_t)b * PAIRS + p] = r;
}

extern "C" void kernel_launch(void* const* d_in, const int* in_sizes, int n_in,
                              void* d_out, int out_size, void* d_ws, size_t ws_size,
                              hipStream_t stream) {
    const float* x    = (const float*)d_in[0];
    const float* kern = (const float*)d_in[1];
    float*       out  = (float*)d_out;

    if (ws_size < WS_NEED) {
        opn_fp32_kernel<<<dim3(PAIRS * 32), dim3(64), 0, stream>>>(x, kern, out);
        return;
    }

    char* ws = (char*)d_ws;
    unsigned short* xhi = (unsigned short*)(ws + XH_OFF);
    unsigned short* xlo = (unsigned short*)(ws + XL_OFF);
    unsigned short* kph = (unsigned short*)(ws + KPH_OFF);
    unsigned short* kpl = (unsigned short*)(ws + KPL_OFF);

    prep_kernel<<<dim3(XSPLIT_BLOCKS + KPACK_BLOCKS), dim3(256), 0, stream>>>(
        x, kern, xhi, xlo, kph, kpl);
    opn_mfma_kernel<<<dim3(PAIRS * 16), dim3(256), 0, stream>>>(
        x, xhi, xlo, kph, kpl, out);
}